// Round 2
// baseline (407.081 us; speedup 1.0000x reference)
//
#include <hip/hip_runtime.h>
#include <cstdint>
#include <cstddef>

#define DIM 16384
#define BSIZE 32
#define MAX_STEPS 9
#define JSUB 256
#define TPB3 1024
#define KPT (DIM / TPB3)  // 16

// ---------------- K0: transpose x [B][D] -> xT [D][B] ----------------
__global__ void k_xpose(const float* __restrict__ x, float* __restrict__ xT) {
    int tid = blockIdx.x * blockDim.x + threadIdx.x;  // 0 .. B*D
    int b = tid >> 14;          // DIM = 2^14
    int j = tid & (DIM - 1);
    xT[(size_t)j * BSIZE + b] = x[tid];
}

// ------- K1: partial[slot][b][c] = sum_{j in slot} x[b][j] * W[j][c] -------
// grid = (DIM/256, nslots), 256 threads, 1 column per thread, 32 batch accumulators.
__global__ __launch_bounds__(256) void k_matmul(
        const float* __restrict__ W, const float* __restrict__ xT,
        float* __restrict__ partial, int jb) {
    __shared__ float ldsx[JSUB * BSIZE];  // 32 KB
    const int c = blockIdx.x * 256 + threadIdx.x;
    const int j0 = blockIdx.y * jb;
    float acc[BSIZE];
#pragma unroll
    for (int i = 0; i < BSIZE; ++i) acc[i] = 0.f;

    for (int js = 0; js < jb; js += JSUB) {
        __syncthreads();  // protect previous sub-chunk's LDS reads
        const float4* src = (const float4*)(xT + (size_t)(j0 + js) * BSIZE);
        float4* dst = (float4*)ldsx;
#pragma unroll
        for (int t = 0; t < (JSUB * BSIZE / 4 / 256); ++t)  // 8
            dst[threadIdx.x + t * 256] = src[threadIdx.x + t * 256];
        __syncthreads();
        const float* wp = W + (size_t)(j0 + js) * DIM + c;
#pragma unroll 4
        for (int jj = 0; jj < JSUB; ++jj) {
            float w = wp[(size_t)jj * DIM];                 // coalesced, 256B/wave
            const float4* xr = (const float4*)(ldsx + jj * BSIZE);  // uniform -> broadcast
#pragma unroll
            for (int q = 0; q < 8; ++q) {
                float4 xv = xr[q];
                acc[q * 4 + 0] = fmaf(xv.x, w, acc[q * 4 + 0]);
                acc[q * 4 + 1] = fmaf(xv.y, w, acc[q * 4 + 1]);
                acc[q * 4 + 2] = fmaf(xv.z, w, acc[q * 4 + 2]);
                acc[q * 4 + 3] = fmaf(xv.w, w, acc[q * 4 + 3]);
            }
        }
    }
    float* pp = partial + (size_t)blockIdx.y * BSIZE * DIM + c;
#pragma unroll
    for (int b = 0; b < BSIZE; ++b) pp[(size_t)b * DIM] = acc[b];
}

// ------- K2: h0[b][c] = sum_slots partial + bias[c] -------
__global__ void k_reduce(const float* __restrict__ partial, const float* __restrict__ bias,
                         float* __restrict__ h0, int nslots) {
    int tid = blockIdx.x * blockDim.x + threadIdx.x;  // b*DIM + c
    int c = tid & (DIM - 1);
    float s = 0.f;
    for (int sl = 0; sl < nslots; ++sl)
        s += partial[(size_t)sl * BSIZE * DIM + tid];
    h0[tid] = s + bias[c];
}

// ---------------- K3 helpers: block-wide reductions (1024 thr = 16 waves) ----------------
__device__ __forceinline__ float block_reduce_max(float v, float* red) {
#pragma unroll
    for (int off = 1; off < 64; off <<= 1)
        v = fmaxf(v, __shfl_xor(v, off));
    int lane = threadIdx.x & 63, wv = threadIdx.x >> 6;
    if (lane == 0) red[wv] = v;
    __syncthreads();
    if (threadIdx.x == 0) {
        float m = red[0];
        for (int w = 1; w < TPB3 / 64; ++w) m = fmaxf(m, red[w]);
        red[0] = m;
    }
    __syncthreads();
    float r = red[0];
    __syncthreads();  // allow red[] reuse
    return r;
}

__device__ __forceinline__ float block_reduce_sum(float v, float* red) {
#pragma unroll
    for (int off = 1; off < 64; off <<= 1)
        v += __shfl_xor(v, off);
    int lane = threadIdx.x & 63, wv = threadIdx.x >> 6;
    if (lane == 0) red[wv] = v;
    __syncthreads();
    if (threadIdx.x == 0) {
        float s = red[0];
        for (int w = 1; w < TPB3 / 64; ++w) s += red[w];
        red[0] = s;
    }
    __syncthreads();
    float r = red[0];
    __syncthreads();
    return r;
}

// argmax with first-index (min idx) tie-break, matching jnp.argmax
__device__ __forceinline__ int block_argmax(float v, int idx, float* redf, int* redi) {
#pragma unroll
    for (int off = 1; off < 64; off <<= 1) {
        float ov = __shfl_xor(v, off);
        int oi = __shfl_xor(idx, off);
        if (ov > v || (ov == v && oi < idx)) { v = ov; idx = oi; }
    }
    int lane = threadIdx.x & 63, wv = threadIdx.x >> 6;
    if (lane == 0) { redf[wv] = v; redi[wv] = idx; }
    __syncthreads();
    if (threadIdx.x == 0) {
        float bv = redf[0]; int bi = redi[0];
        for (int w = 1; w < TPB3 / 64; ++w) {
            float ov = redf[w]; int oi = redi[w];
            if (ov > bv || (ov == bv && oi < bi)) { bv = ov; bi = oi; }
        }
        redi[0] = bi;
    }
    __syncthreads();
    int r = redi[0];
    __syncthreads();
    return r;
}

// ------- K3: per-row sampler. One block per batch row; h, signs in registers. -------
__global__ __launch_bounds__(TPB3) void k_sample(
        const float* __restrict__ x, const float* __restrict__ W,
        const float* __restrict__ h0, const float* __restrict__ gumbel,
        const float* __restrict__ au, const int* __restrict__ radius,
        float* __restrict__ out) {
    __shared__ float redf[TPB3 / 64];
    __shared__ int   redi[TPB3 / 64];
    __shared__ float s_delta;
    const int b = blockIdx.x;
    const int tid = threadIdx.x;

    float h[KPT], sg[KPT];
#pragma unroll
    for (int k = 0; k < KPT; ++k) {
        int c = tid + k * TPB3;
        h[k] = h0[(size_t)b * DIM + c];
        sg[k] = 1.0f - 2.0f * x[(size_t)b * DIM + c];  // exactly +/-1
    }

    // Zx = logsumexp(sg*h*0.5)
    float lmax = -INFINITY;
#pragma unroll
    for (int k = 0; k < KPT; ++k) lmax = fmaxf(lmax, sg[k] * h[k] * 0.5f);
    float m = block_reduce_max(lmax, redf);
    float lsum = 0.f;
#pragma unroll
    for (int k = 0; k < KPT; ++k) lsum += expf(sg[k] * h[k] * 0.5f - m);
    float S = block_reduce_sum(lsum, redf);
    float Zx = logf(S) + m;

    const int rad = radius[b];  // in [1, 9]; steps t >= rad are no-ops in the reference
    for (int t = 0; t < rad; ++t) {
        const float* g = gumbel + ((size_t)t * BSIZE + b) * DIM;
        float best = -INFINITY; int bidx = 0;
#pragma unroll
        for (int k = 0; k < KPT; ++k) {   // ascending c => strict > keeps first max
            int c = tid + k * TPB3;
            float v = sg[k] * h[k] * 0.5f + g[c];
            if (v > best) { best = v; bidx = c; }
        }
        int idx = block_argmax(best, bidx, redf, redi);
        if (tid == (idx & (TPB3 - 1))) {
            int k = idx >> 10;
            s_delta = sg[k];   // delta = (1 - 2*x_old)
            sg[k] = -sg[k];    // flip the bit
        }
        __syncthreads();
        float delta = s_delta;
        const float* wr = W + (size_t)idx * DIM;
#pragma unroll
        for (int k = 0; k < KPT; ++k) {   // rank-1 update: h += delta * W[idx,:]
            int c = tid + k * TPB3;
            h[k] = fmaf(delta, wr[c], h[k]);
        }
        __syncthreads();
    }

    // Zy
    lmax = -INFINITY;
#pragma unroll
    for (int k = 0; k < KPT; ++k) lmax = fmaxf(lmax, sg[k] * h[k] * 0.5f);
    m = block_reduce_max(lmax, redf);
    lsum = 0.f;
#pragma unroll
    for (int k = 0; k < KPT; ++k) lsum += expf(sg[k] * h[k] * 0.5f - m);
    S = block_reduce_sum(lsum, redf);
    float Zy = logf(S) + m;

    int accepted = (expf(Zx - Zy) >= au[b]) ? 1 : 0;
#pragma unroll
    for (int k = 0; k < KPT; ++k) {
        int c = tid + k * TPB3;
        float y = (sg[k] < 0.f) ? 1.f : 0.f;
        out[(size_t)b * DIM + c] = accepted ? y : x[(size_t)b * DIM + c];
    }
}

extern "C" void kernel_launch(void* const* d_in, const int* in_sizes, int n_in,
                              void* d_out, int out_size, void* d_ws, size_t ws_size,
                              hipStream_t stream) {
    (void)in_sizes; (void)n_in; (void)out_size;
    const float* x      = (const float*)d_in[0];
    const float* W      = (const float*)d_in[1];
    const float* bias   = (const float*)d_in[2];
    const float* gumbel = (const float*)d_in[3];
    const float* au     = (const float*)d_in[4];
    const int*   radius = (const int*)d_in[5];
    float* out = (float*)d_out;

    // ws layout: xT (2 MB) | partial (nslots * 2 MB) | h0 (2 MB)
    float* xT = (float*)d_ws;
    size_t xt_elems = (size_t)DIM * BSIZE;
    int nslots = 16;
    while (nslots > 1) {
        size_t need = (xt_elems + (size_t)nslots * BSIZE * DIM + (size_t)BSIZE * DIM) * sizeof(float);
        if (need <= ws_size) break;
        nslots >>= 1;
    }
    float* partial = xT + xt_elems;
    float* h0 = partial + (size_t)nslots * BSIZE * DIM;

    k_xpose<<<(DIM * BSIZE) / 256, 256, 0, stream>>>(x, xT);
    dim3 g1(DIM / 256, nslots);
    k_matmul<<<g1, 256, 0, stream>>>(W, xT, partial, DIM / nslots);
    k_reduce<<<(DIM * BSIZE) / 256, 256, 0, stream>>>(partial, bias, h0, nslots);
    k_sample<<<BSIZE, TPB3, 0, stream>>>(x, W, h0, gumbel, au, radius, out);
}